// Round 3
// baseline (119.012 us; speedup 1.0000x reference)
//
#include <hip/hip_runtime.h>
#include <stdint.h>

#define B_ 1024
#define N_ 128
#define D_ 128
#define H_ 256
#define L_ 64
#define INF_ 0x3FFFFFFF

// ws byte offsets
#define WS_W1   0u          // W1T A-frags: 32768 u16 = 65536 B
#define WS_W2   65536u      // W2 B-frags: 65536 u16 = 131072 B
#define WS_TREE 196608u     // per-graph 3072 B: tnbr[128][4] u32 | inv[128] f32 | wm[128] f32
#define WS_G    3342336u    // pooled g: [1024][256] f32

typedef __attribute__((ext_vector_type(8))) short bf16x8;
typedef __attribute__((ext_vector_type(4))) float f32x4;
typedef __attribute__((ext_vector_type(4))) uint32_t u32x4;
typedef __attribute__((ext_vector_type(2))) uint32_t u32x2;

__device__ __forceinline__ float b2f(uint16_t u) {
    return __uint_as_float(((uint32_t)u) << 16);
}
__device__ __forceinline__ uint16_t f2b(float f) {
    uint32_t u = __float_as_uint(f);
    return (uint16_t)((u + 0x7FFFu + ((u >> 16) & 1u)) >> 16);   // RNE
}
__device__ __forceinline__ uint32_t pack2(float a, float b) {
    return (uint32_t)f2b(a) | ((uint32_t)f2b(b) << 16);
}

// ---------------- weight prep: fragment-linear bf16 layouts in ws ----------------
__global__ void prep_weights(const float* __restrict__ W1, const float* __restrict__ W2,
                             uint16_t* __restrict__ ws) {
    int t = blockIdx.x * 256 + threadIdx.x;
    if (t < 4096) {                       // W1T A-frags: A[m=h][k=f]
        int lane = t & 63, fkb = t >> 6;
        int tm = fkb >> 2, kb = fkb & 3;
        int h  = tm * 16 + (lane & 15);
        int k0 = kb * 32 + (lane >> 4) * 8;
        u32x4 w;
        #pragma unroll
        for (int p = 0; p < 4; ++p)
            w[p] = pack2(W1[(k0 + 2*p) * H_ + h], W1[(k0 + 2*p + 1) * H_ + h]);
        *reinterpret_cast<u32x4*>(&ws[t * 8]) = w;
    } else if (t < 12288) {               // W2 B-frags: B[k][n]
        int t2 = t - 4096;
        int lane = t2 & 63, g = t2 >> 6;
        int tn = g >> 3, kb = g & 7;
        int n  = tn * 16 + (lane & 15);
        int k0 = kb * 32 + (lane >> 4) * 8;
        u32x4 w;
        #pragma unroll
        for (int p = 0; p < 4; ++p)
            w[p] = pack2(W2[(k0 + 2*p) * H_ + n], W2[(k0 + 2*p + 1) * H_ + n]);
        *reinterpret_cast<u32x4*>(&ws[32768 + t2 * 8]) = w;
    }
}

// ---------------- K1: BFS spanning tree per graph ----------------
__global__ __launch_bounds__(256, 4) void tree_kernel(
    const float* __restrict__ adj, uint8_t* __restrict__ wsb)
{
    __shared__ uint32_t adjm[128][4];
    __shared__ __align__(16) uint32_t tnbr[128][4];
    __shared__ int      s_order[128];
    __shared__ int      s_parent[128];
    __shared__ int      s_key[128];
    __shared__ float    s_inv[128];
    __shared__ float    s_wm[128];
    __shared__ uint32_t visw[4], actw[4], newlyw[4];
    __shared__ int      s_root;

    const int tid = threadIdx.x;
    const int b   = blockIdx.x;
    const float* ag = adj + (size_t)b * N_ * N_;

    if (tid < 128) { s_order[tid] = INF_; s_parent[tid] = 0; }
    if (tid < 4)   { visw[tid] = 0u; actw[tid] = 0u; }
    if (tid == 0)  { s_root = 128; }
    {
        const int v = tid >> 1, hf = tid & 1;
        const float4* ag4 = reinterpret_cast<const float4*>(ag + v * N_ + hf * 64);
        uint32_t w0 = 0, w1 = 0;
        #pragma unroll
        for (int i = 0; i < 16; ++i) {
            float4 f = ag4[i];
            uint32_t bs = (f.x > 0.5f ? 1u : 0u) | (f.y > 0.5f ? 2u : 0u) |
                          (f.z > 0.5f ? 4u : 0u) | (f.w > 0.5f ? 8u : 0u);
            int base = i * 4;
            if (base < 32) w0 |= bs << base; else w1 |= bs << (base - 32);
        }
        adjm[v][hf * 2]     = w0;
        adjm[v][hf * 2 + 1] = w1;
    }
    __syncthreads();

    if (tid < 128) {
        uint32_t any = adjm[tid][0] | adjm[tid][1] | adjm[tid][2] | adjm[tid][3];
        if (any) {
            atomicMin(&s_root, tid);
            atomicOr(&actw[tid >> 5], 1u << (tid & 31));
        }
    }
    __syncthreads();
    int counter = 0;
    if (s_root < 128) {
        counter = 1;
        if (tid == 0) {
            s_order[s_root] = 0;
            visw[s_root >> 5] = 1u << (s_root & 31);
        }
    }
    __syncthreads();

    for (int step = 0; step < N_ - 1; ++step) {
        if (tid < 4) newlyw[tid] = 0u;
        __syncthreads();
        int newly = 0, po = INF_, par = 0;
        if (tid < 128 && s_order[tid] >= INF_) {
            #pragma unroll
            for (int w = 0; w < 4; ++w) {
                uint32_t m = adjm[tid][w] & visw[w];
                while (m) {
                    int u = (w << 5) + __ffs(m) - 1; m &= m - 1;
                    int o = s_order[u];
                    if (o < po) { po = o; par = u; }
                }
            }
            newly = (po < INF_);
            if (newly) {
                s_key[tid] = po * N_ + tid;
                atomicOr(&newlyw[tid >> 5], 1u << (tid & 31));
            }
        }
        __syncthreads();
        int myk = newly ? po * N_ + tid : 0x7FFFFFFF;
        int cnt = 0, rank = 0;
        #pragma unroll
        for (int w = 0; w < 4; ++w) {
            uint32_t m = newlyw[w];
            cnt += __popc(m);
            while (m) {
                int u = (w << 5) + __ffs(m) - 1; m &= m - 1;
                rank += (s_key[u] < myk);
            }
        }
        if (newly) {
            s_order[tid]  = counter + rank;
            s_parent[tid] = par;
            atomicOr(&visw[tid >> 5], 1u << (tid & 31));
        }
        counter += cnt;
        __syncthreads();
        if (cnt == 0) break;
    }

    if (tid < 128) { tnbr[tid][0] = 0; tnbr[tid][1] = 0; tnbr[tid][2] = 0; tnbr[tid][3] = 0; }
    __syncthreads();
    if (tid < 128 && s_order[tid] > 0 && s_order[tid] < INF_) {
        int p = s_parent[tid];
        atomicOr(&tnbr[tid][p >> 5], 1u << (p & 31));
        atomicOr(&tnbr[p][tid >> 5], 1u << (tid & 31));
    }
    __syncthreads();
    if (tid < 128) {
        int d = 1 + __popc(tnbr[tid][0]) + __popc(tnbr[tid][1]) +
                    __popc(tnbr[tid][2]) + __popc(tnbr[tid][3]);
        int num = __popc(actw[0]) + __popc(actw[1]) + __popc(actw[2]) + __popc(actw[3]);
        int act = (actw[tid >> 5] >> (tid & 31)) & 1;
        uint8_t* gbase = wsb + WS_TREE + (size_t)b * 3072;
        *reinterpret_cast<u32x4*>(gbase + tid * 16) =
            *reinterpret_cast<u32x4*>(&tnbr[tid][0]);
        reinterpret_cast<float*>(gbase + 2048)[tid] = 1.0f / (float)d;
        reinterpret_cast<float*>(gbase + 2560)[tid] =
            act ? (1.0f / (float)(num > 0 ? num : 1)) : 0.0f;
    }
}

// ---------------- K2: fused GCN compute per graph (512 threads) ----------------
__global__ __launch_bounds__(512, 2) void gcn_kernel(
    const float* __restrict__ x, const uint16_t* __restrict__ ws,
    const uint8_t* __restrict__ wsb,
    const float* __restrict__ b1g, const float* __restrict__ b2g,
    float* __restrict__ wsG)
{
    // sbuf (u16): [0,17920): x [128][140] bf16 (padded rows)
    //             [17920,34304): xa in matmul1 B-frag layout
    //             h1 / M2 frag layouts overwrite [0,32768) after m1/m2
    __shared__ __align__(16) uint16_t sbuf[34304];          // 68608 B
    __shared__ __align__(16) uint32_t tnbr[128][4];
    __shared__ float    s_inv[128];
    __shared__ float    s_wm[128];

    const int tid  = threadIdx.x;
    const int b    = blockIdx.x;
    const int wid  = tid >> 6;
    const int lane = tid & 63;
    const int l15  = lane & 15;
    const int q    = lane >> 4;

    const float* xg = x + (size_t)b * N_ * D_;

    // ---------- load x (bf16, padded rows) + tree data ----------
    {
        const float4* xg4 = reinterpret_cast<const float4*>(xg);
        #pragma unroll
        for (int i = 0; i < 8; ++i) {
            int idx = tid + i * 512;                 // 4096 float4
            float4 v = xg4[idx];
            int row = idx >> 5, c4 = (idx & 31) * 4;
            u32x2 w; w[0] = pack2(v.x, v.y); w[1] = pack2(v.z, v.w);
            *reinterpret_cast<u32x2*>(&sbuf[row * 140 + c4]) = w;
        }
    }
    if (tid < 128) {
        const uint8_t* gbase = wsb + WS_TREE + (size_t)b * 3072;
        u32x4 t4 = *reinterpret_cast<const u32x4*>(gbase + tid * 16);
        tnbr[tid][0] = t4[0]; tnbr[tid][1] = t4[1];
        tnbr[tid][2] = t4[2]; tnbr[tid][3] = t4[3];
        s_inv[tid] = reinterpret_cast<const float*>(gbase + 2048)[tid];
        s_wm[tid]  = reinterpret_cast<const float*>(gbase + 2560)[tid];
    }
    __syncthreads();

    // ---------- aggregation 1 (tree gather): xa = T̂norm @ x -> m1 B-frag layout ----------
    {
        const int v = tid >> 2, part = tid & 3;      // part = 32-wide d-chunk = kb
        float acc[32];
        const uint16_t* xr = &sbuf[v * 140 + part * 32];
        #pragma unroll
        for (int i = 0; i < 32; i += 4) {
            uint64_t w = *reinterpret_cast<const uint64_t*>(xr + i);
            acc[i]   = b2f((uint16_t)w);
            acc[i+1] = b2f((uint16_t)(w >> 16));
            acc[i+2] = b2f((uint16_t)(w >> 32));
            acc[i+3] = b2f((uint16_t)(w >> 48));
        }
        #pragma unroll
        for (int wi = 0; wi < 4; ++wi) {
            uint32_t m = tnbr[v][wi];
            while (m) {
                int u = (wi << 5) + __ffs(m) - 1; m &= m - 1;
                const uint16_t* ur = &sbuf[u * 140 + part * 32];
                #pragma unroll
                for (int i = 0; i < 32; i += 4) {
                    uint64_t w = *reinterpret_cast<const uint64_t*>(ur + i);
                    acc[i]   += b2f((uint16_t)w);
                    acc[i+1] += b2f((uint16_t)(w >> 16));
                    acc[i+2] += b2f((uint16_t)(w >> 32));
                    acc[i+3] += b2f((uint16_t)(w >> 48));
                }
            }
        }
        const float inv = s_inv[v];
        const int tnx = v >> 4, v15 = v & 15;
        #pragma unroll
        for (int qq = 0; qq < 4; ++qq) {
            int lo = qq * 8;
            u32x4 w;
            w[0] = pack2(acc[lo  ] * inv, acc[lo+1] * inv);
            w[1] = pack2(acc[lo+2] * inv, acc[lo+3] * inv);
            w[2] = pack2(acc[lo+4] * inv, acc[lo+5] * inv);
            w[3] = pack2(acc[lo+6] * inv, acc[lo+7] * inv);
            *reinterpret_cast<u32x4*>(
                &sbuf[17920 + (((tnx * 4 + part) * 64) + qq * 16 + v15) * 8]) = w;
        }
    }
    __syncthreads();

    // ---------- matmul1 (swapped): h1^T = W1^T @ xa^T ----------
    // wave owns H-tiles tm = wid*2+j (j<2), all 8 node-tiles. C lane: m=h, n=node.
    {
        f32x4 acc1[2][8];
        #pragma unroll
        for (int j = 0; j < 2; ++j)
            #pragma unroll
            for (int t = 0; t < 8; ++t) acc1[j][t] = (f32x4){0.f, 0.f, 0.f, 0.f};
        const bf16x8* wsA = reinterpret_cast<const bf16x8*>(ws);
        for (int kb = 0; kb < 4; ++kb) {
            bf16x8 afr[2], bfr[8];
            #pragma unroll
            for (int j = 0; j < 2; ++j)
                afr[j] = wsA[((wid * 2 + j) * 4 + kb) * 64 + lane];
            #pragma unroll
            for (int t = 0; t < 8; ++t)
                bfr[t] = *reinterpret_cast<const bf16x8*>(
                    &sbuf[17920 + ((t * 4 + kb) * 64 + lane) * 8]);
            #pragma unroll
            for (int j = 0; j < 2; ++j)
                #pragma unroll
                for (int t = 0; t < 8; ++t)
                    acc1[j][t] = __builtin_amdgcn_mfma_f32_16x16x32_bf16(
                        afr[j], bfr[t], acc1[j][t], 0, 0, 0);
        }
        __syncthreads();   // xa reads done; write h1 (bias+relu) into m2 A-frag layout
        #pragma unroll
        for (int j = 0; j < 2; ++j) {
            int tm = wid * 2 + j;
            int m0 = tm * 16 + q * 4;
            f32x4 bb = *reinterpret_cast<const f32x4*>(b1g + m0);
            int kbh = tm >> 1;
            int sl  = l15 + 16 * ((2 * tm + (q >> 1)) & 3);
            #pragma unroll
            for (int t = 0; t < 8; ++t) {
                f32x4 v = acc1[j][t];
                float v0 = fmaxf(v[0] + bb[0], 0.f), v1 = fmaxf(v[1] + bb[1], 0.f);
                float v2 = fmaxf(v[2] + bb[2], 0.f), v3 = fmaxf(v[3] + bb[3], 0.f);
                u32x2 w; w[0] = pack2(v0, v1); w[1] = pack2(v2, v3);
                *reinterpret_cast<u32x2*>(
                    &sbuf[((t * 8 + kbh) * 64 + sl) * 8 + (q & 1) * 4]) = w;
            }
        }
    }
    __syncthreads();

    // ---------- matmul2: M2 = h1 @ W2 ----------
    // wave owns H-out tiles tn = wid*2+j, all 8 node-tiles. C lane: m=node, n=h.
    {
        f32x4 acc2[8][2];
        #pragma unroll
        for (int tm = 0; tm < 8; ++tm)
            #pragma unroll
            for (int j = 0; j < 2; ++j) acc2[tm][j] = (f32x4){0.f, 0.f, 0.f, 0.f};
        const bf16x8* wsB = reinterpret_cast<const bf16x8*>(ws + 32768);
        for (int kb = 0; kb < 8; ++kb) {
            bf16x8 a2[8], bfr[2];
            #pragma unroll
            for (int tm = 0; tm < 8; ++tm)
                a2[tm] = *reinterpret_cast<const bf16x8*>(
                    &sbuf[((tm * 8 + kb) * 64 + lane) * 8]);
            #pragma unroll
            for (int j = 0; j < 2; ++j)
                bfr[j] = wsB[((wid * 2 + j) * 8 + kb) * 64 + lane];
            #pragma unroll
            for (int tm = 0; tm < 8; ++tm)
                #pragma unroll
                for (int j = 0; j < 2; ++j)
                    acc2[tm][j] = __builtin_amdgcn_mfma_f32_16x16x32_bf16(
                        a2[tm], bfr[j], acc2[tm][j], 0, 0, 0);
        }
        __syncthreads();   // h1 reads done; write M2 into agg2 B-frag layout
        #pragma unroll
        for (int tm = 0; tm < 8; ++tm) {
            int kbh = tm >> 1;
            int sl  = l15 + 16 * ((2 * tm + (q >> 1)) & 3);
            #pragma unroll
            for (int j = 0; j < 2; ++j) {
                int tn = wid * 2 + j;
                f32x4 v = acc2[tm][j];
                u32x2 w; w[0] = pack2(v[0], v[1]); w[1] = pack2(v[2], v[3]);
                *reinterpret_cast<u32x2*>(
                    &sbuf[((tn * 4 + kbh) * 64 + sl) * 8 + (q & 1) * 4]) = w;
            }
        }
    }
    __syncthreads();

    // ---------- aggregation 2 via MFMA + fused scale/bias/relu/mask/pool ----------
    {
        f32x4 acc3[8][2];
        #pragma unroll
        for (int tm = 0; tm < 8; ++tm)
            #pragma unroll
            for (int j = 0; j < 2; ++j) acc3[tm][j] = (f32x4){0.f, 0.f, 0.f, 0.f};
        for (int kb = 0; kb < 4; ++kb) {
            bf16x8 a3[8], bfr[2];
            #pragma unroll
            for (int tm = 0; tm < 8; ++tm) {
                int v = tm * 16 + l15;
                uint32_t word = tnbr[v][kb];
                uint32_t by = (word >> (q * 8)) & 0xFFu;
                if ((v >> 3) == kb * 4 + q) by |= 1u << (v & 7);
                u32x4 p;
                #pragma unroll
                for (int pp = 0; pp < 4; ++pp)
                    p[pp] = (((by >> (2 * pp)) & 1u) ? 0x3F80u : 0u) |
                            (((by >> (2 * pp + 1)) & 1u) ? 0x3F800000u : 0u);
                a3[tm] = __builtin_bit_cast(bf16x8, p);
            }
            #pragma unroll
            for (int j = 0; j < 2; ++j)
                bfr[j] = *reinterpret_cast<const bf16x8*>(
                    &sbuf[(((wid * 2 + j) * 4 + kb) * 64 + lane) * 8]);
            #pragma unroll
            for (int tm = 0; tm < 8; ++tm)
                #pragma unroll
                for (int j = 0; j < 2; ++j)
                    acc3[tm][j] = __builtin_amdgcn_mfma_f32_16x16x32_bf16(
                        a3[tm], bfr[j], acc3[tm][j], 0, 0, 0);
        }
        float ps[2] = {0.f, 0.f};
        #pragma unroll
        for (int tm = 0; tm < 8; ++tm) {
            int v0 = tm * 16 + q * 4;
            f32x4 iv = *reinterpret_cast<const f32x4*>(&s_inv[v0]);
            f32x4 wm = *reinterpret_cast<const f32x4*>(&s_wm[v0]);
            #pragma unroll
            for (int j = 0; j < 2; ++j) {
                float bc = b2g[(wid * 2 + j) * 16 + l15];
                f32x4 a = acc3[tm][j];
                #pragma unroll
                for (int r = 0; r < 4; ++r)
                    ps[j] += fmaxf(fmaf(a[r], iv[r], bc), 0.f) * wm[r];
            }
        }
        #pragma unroll
        for (int j = 0; j < 2; ++j) {
            ps[j] += __shfl_xor(ps[j], 16);
            ps[j] += __shfl_xor(ps[j], 32);
        }
        if (q == 0) {
            #pragma unroll
            for (int j = 0; j < 2; ++j)
                wsG[(size_t)b * 256 + (wid * 2 + j) * 16 + l15] = ps[j];
        }
    }
}

// ---------------- K3: heads GEMV: out = g @ {Wmu,Wlv} + bias ----------------
__global__ __launch_bounds__(128, 8) void heads_kernel(
    const float* __restrict__ wsG,
    const float* __restrict__ Wmu, const float* __restrict__ bmu,
    const float* __restrict__ Wlv, const float* __restrict__ blv,
    float* __restrict__ out)
{
    __shared__ float sg[256];
    const int tid = threadIdx.x, b = blockIdx.x;
    const float* g = wsG + (size_t)b * 256;
    sg[tid]       = g[tid];
    sg[tid + 128] = g[tid + 128];
    __syncthreads();
    const int which = tid >> 6, l = tid & 63;
    const float* W = which ? Wlv : Wmu;
    float acc = which ? blv[l] : bmu[l];
    #pragma unroll 8
    for (int cc = 0; cc < 256; ++cc)
        acc = fmaf(sg[cc], W[cc * L_ + l], acc);
    out[(size_t)which * B_ * L_ + (size_t)b * L_ + l] = acc;
}

extern "C" void kernel_launch(void* const* d_in, const int* in_sizes, int n_in,
                              void* d_out, int out_size, void* d_ws, size_t ws_size,
                              hipStream_t stream) {
    const float* x   = (const float*)d_in[0];
    const float* adj = (const float*)d_in[1];
    const float* W1  = (const float*)d_in[2];
    const float* b1  = (const float*)d_in[3];
    const float* W2  = (const float*)d_in[4];
    const float* b2  = (const float*)d_in[5];
    const float* Wmu = (const float*)d_in[6];
    const float* bmu = (const float*)d_in[7];
    const float* Wlv = (const float*)d_in[8];
    const float* blv = (const float*)d_in[9];
    float* out = (float*)d_out;
    uint8_t*  wsb = (uint8_t*)d_ws;
    uint16_t* ws  = (uint16_t*)d_ws;
    float*    wsG = (float*)(wsb + WS_G);

    hipLaunchKernelGGL(prep_weights, dim3(48), dim3(256), 0, stream, W1, W2, ws);
    hipLaunchKernelGGL(tree_kernel, dim3(B_), dim3(256), 0, stream, adj, wsb);
    hipLaunchKernelGGL(gcn_kernel, dim3(B_), dim3(512), 0, stream,
                       x, ws, wsb, b1, b2, wsG);
    hipLaunchKernelGGL(heads_kernel, dim3(B_), dim3(128), 0, stream,
                       wsG, Wmu, bmu, Wlv, blv, out);
}